// Round 13
// baseline (533.492 us; speedup 1.0000x reference)
//
#include <hip/hip_runtime.h>

#define N_NODES_C 50000
#define N_EDGES_C 640000
#define HD 128

typedef float f32x4 __attribute__((ext_vector_type(4)));
typedef float f32x2 __attribute__((ext_vector_type(2)));
typedef short short8 __attribute__((ext_vector_type(8)));
typedef int   int4v  __attribute__((ext_vector_type(4)));

// d_out layout (floats): [node_out 6.4M][edge_index 1.28M][edge_out 81.92M]
#define OUT_NODE 0
#define OUT_IDX  6400000
#define OUT_EDGE 7680000

// workspace layout part 1 (shorts = bf16), transposed weights [n][k]
#define EW0T 0        // [0,16384): We^T [128][128]; [16384,49152): WP^T [256][128] (Ws|Wr)
#define WPT  16384
#define EW1T 49152    // 128x128
#define EW2T 65536
#define EW3T 81920
#define NW0T 98304    // 128x256
#define NW1T 131072
#define NW2T 147456
#define NW3T 163840
#define WTOT 180224   // shorts

// workspace layout part 2 (ints; int-index into d_ws)
#define OFFS_I  98304    // 50001 ints: CSR row starts
#define CURS_I  148352   // 50000 ints: counts -> cursor -> row ends
#define ELIST_I 198400   // 640000 ints

// workspace part 3: P table, bf16 [50000][256]
#define PTAB_S 1676800
// workspace part 4 (optional): upd_edge bf16 [640000][128]
#define UPD_S  14476800
#define UPD_END_BYTES ((size_t)(UPD_S + (size_t)N_EDGES_C * HD) * 2)

__device__ inline short f2bf(float f) {
  unsigned u = __builtin_bit_cast(unsigned, f);
  u += 0x7fffu + ((u >> 16) & 1u);   // RNE
  return (short)(u >> 16);
}
__device__ inline float bf2f(short s) {
  unsigned u = ((unsigned)(unsigned short)s) << 16;
  return __builtin_bit_cast(float, u);
}
__device__ inline unsigned cvtpk(float a, float b) {
  unsigned r;
  asm("v_cvt_pk_bf16_f32 %0, %1, %2" : "=v"(r) : "v"(a), "v"(b));
  return r;
}

// LDS index swizzle for bf16 tiles [R][136]: XOR col bits 3-4 with (row>>2)&3 (b128-safe).
__device__ inline int swz(int row, int col) { return row * 136 + (col ^ (((row >> 2) & 3) << 3)); }

// ---------------- prep (+ fused receiver histogram) ----------------
__global__ void prep_kernel(const float* __restrict__ ew0, const float* __restrict__ ew1,
                            const float* __restrict__ ew2, const float* __restrict__ ew3,
                            const float* __restrict__ nw0, const float* __restrict__ nw1,
                            const float* __restrict__ nw2, const float* __restrict__ nw3,
                            const int* __restrict__ eidx,
                            float* __restrict__ out, short* __restrict__ wbuf)
{
  int* counts = (int*)wbuf + CURS_I;   // zeroed by hipMemsetAsync before this kernel
  const int total = 1280000 + WTOT;
  for (int i = blockIdx.x * blockDim.x + threadIdx.x; i < total; i += gridDim.x * blockDim.x) {
    if (i < 1280000) {
      int v = eidx[i];
      out[OUT_IDX + i] = (float)v;
      if (i >= 640000) atomicAdd(&counts[v], 1);   // receiver histogram
    } else {
      int j = i - 1280000;
      short v;
      if (j < WPT)       { int n = j >> 7, k = j & 127; v = f2bf(ew0[(256 + k) * HD + n]); }        // We^T
      else if (j < EW1T) { int j2 = j - WPT, n = j2 >> 7, k = j2 & 127;
                           v = f2bf(ew0[((n < 128 ? 0 : 128) + k) * HD + (n & 127)]); }             // WP^T
      else if (j < EW2T) { int t2 = j - EW1T, n = t2 >> 7, k = t2 & 127; v = f2bf(ew1[k * HD + n]); }
      else if (j < EW3T) { int t2 = j - EW2T, n = t2 >> 7, k = t2 & 127; v = f2bf(ew2[k * HD + n]); }
      else if (j < NW0T) { int t2 = j - EW3T, n = t2 >> 7, k = t2 & 127; v = f2bf(ew3[k * HD + n]); }
      else if (j < NW1T) { int t2 = j - NW0T, n = t2 >> 8, k = t2 & 255; v = f2bf(nw0[k * HD + n]); }
      else if (j < NW2T) { int t2 = j - NW1T, n = t2 >> 7, k = t2 & 127; v = f2bf(nw1[k * HD + n]); }
      else if (j < NW3T) { int t2 = j - NW2T, n = t2 >> 7, k = t2 & 127; v = f2bf(nw2[k * HD + n]); }
      else               { int t2 = j - NW3T, n = t2 >> 7, k = t2 & 127; v = f2bf(nw3[k * HD + n]); }
      wbuf[j] = v;
    }
  }
}

// ---------------- shared 512-thr M=64 helpers (8 waves x 16 cols) ----------------
__device__ inline void zacc4(f32x4 acc[4]) {
  #pragma unroll
  for (int i = 0; i < 4; ++i) { f32x4 z = {0.f, 0.f, 0.f, 0.f}; acc[i] = z; }
}

// A: LDS [64][136] bf16 (swizzled). Wt: [128][Kw] bf16 global (L2-hot). Wave w owns cols w*16..+15.
__device__ inline void mlp16k(const short* __restrict__ Ab, const short* __restrict__ Wt,
                              int Kw, int k0, f32x4 acc[4], int lr, int kg, int w)
{
  const short* wp = Wt + (w * 16 + lr) * Kw + k0 + kg * 8;
  #pragma unroll
  for (int ks = 0; ks < 4; ++ks) {
    short8 b = *(const short8*)(wp + ks * 32);
    #pragma unroll
    for (int mf = 0; mf < 4; ++mf) {
      short8 a = *(const short8*)(Ab + swz(mf * 16 + lr, kg * 8 + ks * 32));
      acc[mf] = __builtin_amdgcn_mfma_f32_16x16x32_bf16(a, b, acc[mf], 0, 0, 0);
    }
  }
}

__device__ inline void wb16_bf16(short* __restrict__ dst, const float* __restrict__ bias,
                                 f32x4 acc[4], int lr, int kg, int w, bool relu)
{
  const int col = w * 16 + lr;
  const float bv = bias[col];
  #pragma unroll
  for (int mf = 0; mf < 4; ++mf) {
    const int row = mf * 16 + kg * 4;
    float v0 = acc[mf][0] + bv, v1 = acc[mf][1] + bv;
    float v2 = acc[mf][2] + bv, v3 = acc[mf][3] + bv;
    if (relu) { v0 = fmaxf(v0, 0.f); v1 = fmaxf(v1, 0.f); v2 = fmaxf(v2, 0.f); v3 = fmaxf(v3, 0.f); }
    unsigned u0 = cvtpk(v0, v1), u1 = cvtpk(v2, v3);
    dst[swz(row + 0, col)] = (short)u0;
    dst[swz(row + 1, col)] = (short)(u0 >> 16);
    dst[swz(row + 2, col)] = (short)u1;
    dst[swz(row + 3, col)] = (short)(u1 >> 16);
  }
}

__device__ inline void wb16_plain(short* __restrict__ dst, f32x4 acc[4], int lr, int kg, int w)
{
  const int col = w * 16 + lr;
  #pragma unroll
  for (int mf = 0; mf < 4; ++mf) {
    const int row = mf * 16 + kg * 4;
    unsigned u0 = cvtpk(acc[mf][0], acc[mf][1]);
    unsigned u1 = cvtpk(acc[mf][2], acc[mf][3]);
    dst[swz(row + 0, col)] = (short)u0;
    dst[swz(row + 1, col)] = (short)(u0 >> 16);
    dst[swz(row + 2, col)] = (short)u1;
    dst[swz(row + 3, col)] = (short)(u1 >> 16);
  }
}

__device__ inline int4v pack8(float a0, float a1, float a2, float a3,
                              float a4, float a5, float a6, float a7) {
  int4v iv;
  iv[0] = (int)cvtpk(a0, a1);
  iv[1] = (int)cvtpk(a2, a3);
  iv[2] = (int)cvtpk(a4, a5);
  iv[3] = (int)cvtpk(a6, a7);
  return iv;
}

// ---------------- node_partial (+ tail-block CSR scan): 512 thr ----------------
#define NP_BLOCKS ((N_NODES_C + 63) / 64)   // 782

__global__ __launch_bounds__(512, 8) void node_partial_kernel(
    const float* __restrict__ nodef, short* __restrict__ wbuf)
{
  __shared__ short lds[2 * 64 * 136];

  // ---- tail block: vectorized CSR scan (counts -> offs + cursor init) ----
  if ((int)blockIdx.x == NP_BLOCKS) {
    int* wsi = (int*)wbuf;
    int* counts = wsi + CURS_I;
    int* offs = wsi + OFFS_I;
    int* tsum = (int*)lds;
    const int t = (int)threadIdx.x;
    const int per = 100;                        // 512*100 >= 50000; 100 % 4 == 0
    const int base = t * per;
    const int lim = (base + per < N_NODES_C) ? base + per : N_NODES_C;
    int s = 0;
    for (int j = base; j < lim; j += 4) {
      int4v c = *(const int4v*)(counts + j);
      s += c[0] + c[1] + c[2] + c[3];
    }
    tsum[t] = s;
    __syncthreads();
    for (int off = 1; off < 512; off <<= 1) {
      int v = tsum[t];
      int add = (t >= off) ? tsum[t - off] : 0;
      __syncthreads();
      tsum[t] = v + add;
      __syncthreads();
    }
    int run = (t == 0) ? 0 : tsum[t - 1];
    for (int j = base; j < lim; j += 4) {
      int4v c = *(const int4v*)(counts + j);
      int4v v;
      v[0] = run; run += c[0];
      v[1] = run; run += c[1];
      v[2] = run; run += c[2];
      v[3] = run; run += c[3];
      *(int4v*)(offs + j) = v;
      *(int4v*)(counts + j) = v;                // cursor init
    }
    if (t == 511) offs[N_NODES_C] = tsum[511];
    return;
  }

  short* B1 = lds;
  short* B2 = lds + 64 * 136;
  short* ptab = wbuf + PTAB_S;

  const int t = (int)threadIdx.x;
  const int lane = t & 63;
  const int w = t >> 6;
  const int lr = lane & 15;
  const int kg = lane >> 4;
  const int n0 = (int)blockIdx.x * 64;

  #pragma unroll
  for (int p = 0; p < 2; ++p) {
    int idx = p * 512 + t;
    int row = idx >> 4;
    int kc = idx & 15;
    int n = n0 + row;
    int ns = n < N_NODES_C ? n : 0;
    const float* src = nodef + (size_t)ns * HD + kc * 8;
    f32x4 v0 = *(const f32x4*)src;
    f32x4 v1 = *(const f32x4*)(src + 4);
    *(int4v*)(B1 + swz(row, kc * 8)) =
        pack8(v0[0], v0[1], v0[2], v0[3], v1[0], v1[1], v1[2], v1[3]);
  }
  __syncthreads();

  f32x4 acc[4];
  #pragma unroll 1
  for (int h = 0; h < 2; ++h) {
    zacc4(acc);
    mlp16k(B1, wbuf + WPT + h * (128 * 128), 128, 0, acc, lr, kg, w);
    wb16_plain(B2, acc, lr, kg, w);
    __syncthreads();
    #pragma unroll
    for (int p = 0; p < 2; ++p) {
      int idx = p * 512 + t;
      int row = idx >> 4;
      int kc = idx & 15;
      int n = n0 + row;
      if (n < N_NODES_C) {
        short8 sv = *(const short8*)(B2 + swz(row, kc * 8));
        *(short8*)(ptab + (size_t)n * 256 + h * 128 + kc * 8) = sv;
      }
    }
    __syncthreads();
  }
}

// ---------------- edge kernel: M=64, 512 thr, bf16 h3 epilogue, stage-fused CSR-fill ----------------
template<bool WRITE_UPD>
__global__ __launch_bounds__(512, 8) void edge_kernel(
    const float* __restrict__ eattr, const int* __restrict__ eidx,
    const float* __restrict__ b0, const float* __restrict__ b1,
    const float* __restrict__ b2, const float* __restrict__ b3,
    const float* __restrict__ gam, const float* __restrict__ bet,
    short* __restrict__ wbuf, float* __restrict__ out)
{
  __shared__ short lds[2 * 64 * 136];   // 34816 B -> 4 blocks/CU -> 32 waves/CU
  short* B1 = lds;
  short* B2 = lds + 64 * 136;

  const int t = (int)threadIdx.x;
  const int w = t >> 6;                 // 0..7
  const int lane = t & 63;
  const int lr = lane & 15;
  const int kg = lane >> 4;
  const int e0 = (int)blockIdx.x * 64;
  const int* senders = eidx;
  const int* recvs = eidx + N_EDGES_C;
  const short* ptab = wbuf + PTAB_S;
  short* upd = wbuf + UPD_S;
  int* wsi = (int*)wbuf;
  int* cursor = wsi + CURS_I;
  int* elist = wsi + ELIST_I;

  f32x4 acc[4];

  // ---- stage: eattr -> B1 (bf16), G = Ps[s]+Pr[r] -> B2 (bf16); fused CSR-fill ----
  #pragma unroll
  for (int p = 0; p < 2; ++p) {
    int idx = p * 512 + t;
    int row = idx >> 4;
    int kc = idx & 15;
    int e = e0 + row;
    const float* src = eattr + (size_t)e * HD + kc * 8;
    f32x4 v0 = *(const f32x4*)src;
    f32x4 v1 = *(const f32x4*)(src + 4);
    *(int4v*)(B1 + swz(row, kc * 8)) =
        pack8(v0[0], v0[1], v0[2], v0[3], v1[0], v1[1], v1[2], v1[3]);

    int s = senders[e], r = recvs[e];
    if (kc == 0) {                      // fused fill: 1 thread/edge
      int pos = atomicAdd(&cursor[r], 1);
      elist[pos] = e;
    }
    short8 ps = *(const short8*)(ptab + (size_t)s * 256 + kc * 8);
    short8 pr = *(const short8*)(ptab + (size_t)r * 256 + 128 + kc * 8);
    float g0 = bf2f(ps[0]) + bf2f(pr[0]), g1 = bf2f(ps[1]) + bf2f(pr[1]);
    float g2 = bf2f(ps[2]) + bf2f(pr[2]), g3 = bf2f(ps[3]) + bf2f(pr[3]);
    float g4 = bf2f(ps[4]) + bf2f(pr[4]), g5 = bf2f(ps[5]) + bf2f(pr[5]);
    float g6 = bf2f(ps[6]) + bf2f(pr[6]), g7 = bf2f(ps[7]) + bf2f(pr[7]);
    *(int4v*)(B2 + swz(row, kc * 8)) = pack8(g0, g1, g2, g3, g4, g5, g6, g7);
  }
  __syncthreads();

  // ---- layer 0: Ep = eattr @ We^T; h0 = relu(Ep + G + b0) -> B2 ----
  zacc4(acc);
  mlp16k(B1, wbuf + EW0T, 128, 0, acc, lr, kg, w);
  {
    const int col = w * 16 + lr;
    const float bv = b0[col];
    #pragma unroll
    for (int mf = 0; mf < 4; ++mf) {
      const int row = mf * 16 + kg * 4;
      float v0 = fmaxf(acc[mf][0] + bf2f(B2[swz(row + 0, col)]) + bv, 0.f);
      float v1 = fmaxf(acc[mf][1] + bf2f(B2[swz(row + 1, col)]) + bv, 0.f);
      float v2 = fmaxf(acc[mf][2] + bf2f(B2[swz(row + 2, col)]) + bv, 0.f);
      float v3 = fmaxf(acc[mf][3] + bf2f(B2[swz(row + 3, col)]) + bv, 0.f);
      unsigned u0 = cvtpk(v0, v1), u1 = cvtpk(v2, v3);
      B2[swz(row + 0, col)] = (short)u0;
      B2[swz(row + 1, col)] = (short)(u0 >> 16);
      B2[swz(row + 2, col)] = (short)u1;
      B2[swz(row + 3, col)] = (short)(u1 >> 16);
    }
  }
  __syncthreads();

  // ---- layer 1: B2 -> B1 ----
  zacc4(acc);
  mlp16k(B2, wbuf + EW1T, 128, 0, acc, lr, kg, w);
  wb16_bf16(B1, b1, acc, lr, kg, w, true);
  __syncthreads();

  // ---- layer 2: B1 -> B2 ----
  zacc4(acc);
  mlp16k(B1, wbuf + EW2T, 128, 0, acc, lr, kg, w);
  wb16_bf16(B2, b2, acc, lr, kg, w, true);
  __syncthreads();

  // ---- layer 3: B2 -> B1 (bf16 h3 + bias, no relu) ----
  zacc4(acc);
  mlp16k(B2, wbuf + EW3T, 128, 0, acc, lr, kg, w);
  wb16_bf16(B1, b3, acc, lr, kg, w, false);
  __syncthreads();

  // ---- LayerNorm + residual store (+ upd bf16) ----
  {
    const int row = t >> 3;      // 0..63
    const int q = t & 7;         // 8 threads/row, 16 cols each
    const int e = e0 + row;
    const int cxor8 = ((row >> 2) & 3) << 3;   // swz col XOR (8-block preserving)
    float hv[16];
    float sum = 0.f, ss = 0.f;
    #pragma unroll
    for (int j = 0; j < 2; ++j) {
      const int truebase = q * 16 + j * 8;
      short8 hb = *(const short8*)(B1 + row * 136 + (truebase ^ cxor8));
      #pragma unroll
      for (int x = 0; x < 8; ++x) {
        float v = bf2f(hb[x]);
        hv[j * 8 + x] = v;
        sum += v;
        ss += v * v;
      }
    }
    sum += __shfl_xor(sum, 1, 64); sum += __shfl_xor(sum, 2, 64); sum += __shfl_xor(sum, 4, 64);
    ss  += __shfl_xor(ss, 1, 64);  ss  += __shfl_xor(ss, 2, 64);  ss  += __shfl_xor(ss, 4, 64);
    const float mu = sum * (1.f / 128.f);
    const float var = ss * (1.f / 128.f) - mu * mu;
    const float rs = rsqrtf(var + 1e-5f);
    #pragma unroll
    for (int j = 0; j < 2; ++j) {
      const int truebase = q * 16 + j * 8;
      float o[8];
      #pragma unroll
      for (int h = 0; h < 2; ++h) {
        f32x4 g4 = *(const f32x4*)(gam + truebase + h * 4);
        f32x4 b4 = *(const f32x4*)(bet + truebase + h * 4);
        f32x4 ea = *(const f32x4*)(eattr + (size_t)e * HD + truebase + h * 4);
        f32x4 res;
        #pragma unroll
        for (int x = 0; x < 4; ++x) {
          float ov = (hv[j * 8 + h * 4 + x] - mu) * rs * g4[x] + b4[x];
          o[h * 4 + x] = ov;
          res[x] = ea[x] + ov;
        }
        *(f32x4*)(out + OUT_EDGE + (size_t)e * HD + truebase + h * 4) = res;
      }
      if (WRITE_UPD) {
        int4v uu;
        uu[0] = (int)cvtpk(o[0], o[1]);
        uu[1] = (int)cvtpk(o[2], o[3]);
        uu[2] = (int)cvtpk(o[4], o[5]);
        uu[3] = (int)cvtpk(o[6], o[7]);
        *(int4v*)(upd + (size_t)e * HD + truebase) = uu;
      }
    }
  }
}

// ---------------- agg fallback: reads edge_out and eattr (f32), subtracts ----------------
__global__ __launch_bounds__(256, 8) void agg_kernel(
    const float* __restrict__ eattr, const short* __restrict__ wbuf,
    float* __restrict__ out)
{
  const int* wsi = (const int*)wbuf;
  const int* offs = wsi + OFFS_I;
  const int* ends = wsi + CURS_I;
  const int* elist = wsi + ELIST_I;

  const int t = (int)threadIdx.x;
  const int lane = t & 63;
  const int n = (int)blockIdx.x * 4 + (t >> 6);
  if (n >= N_NODES_C) return;

  const int start = offs[n];
  const int end = ends[n];
  f32x2 acc0 = {0.f, 0.f};
  f32x2 acc1 = {0.f, 0.f};
  const float* eo_base = out + OUT_EDGE + lane * 2;
  const float* ea_base = eattr + lane * 2;
  int j = start;
  for (; j + 1 < end; j += 2) {
    const int ex = elist[j];
    const int ey = elist[j + 1];
    f32x2 eox = *(const f32x2*)(eo_base + (size_t)ex * HD);
    f32x2 eax = *(const f32x2*)(ea_base + (size_t)ex * HD);
    f32x2 eoy = *(const f32x2*)(eo_base + (size_t)ey * HD);
    f32x2 eay = *(const f32x2*)(ea_base + (size_t)ey * HD);
    acc0[0] += eox[0] - eax[0];
    acc0[1] += eox[1] - eax[1];
    acc1[0] += eoy[0] - eay[0];
    acc1[1] += eoy[1] - eay[1];
  }
  if (j < end) {
    const int ex = elist[j];
    f32x2 eox = *(const f32x2*)(eo_base + (size_t)ex * HD);
    f32x2 eax = *(const f32x2*)(ea_base + (size_t)ex * HD);
    acc0[0] += eox[0] - eax[0];
    acc0[1] += eox[1] - eax[1];
  }
  acc0[0] += acc1[0];
  acc0[1] += acc1[1];
  *(f32x2*)(out + OUT_NODE + (size_t)n * HD + lane * 2) = acc0;
}

// ---------------- node kernel: M=64, 512 thr (FUSED_AGG gathers upd via CSR in c=1) ----------------
template<bool FUSED_AGG>
__global__ __launch_bounds__(512, 8) void node_kernel(
    const float* __restrict__ nodef,
    const float* __restrict__ b0, const float* __restrict__ b1,
    const float* __restrict__ b2, const float* __restrict__ b3,
    const float* __restrict__ gam, const float* __restrict__ bet,
    const short* __restrict__ wbuf, float* __restrict__ out)
{
  __shared__ short lds[2 * 64 * 136];
  short* B1 = lds;
  short* B2 = lds + 64 * 136;

  const int t = (int)threadIdx.x;
  const int lane = t & 63;
  const int w = t >> 6;
  const int lr = lane & 15;
  const int kg = lane >> 4;
  const int n0 = (int)blockIdx.x * 64;

  const int* wsi = (const int*)wbuf;
  const int* offs = wsi + OFFS_I;
  const int* ends = wsi + CURS_I;
  const int* elist = wsi + ELIST_I;
  const short* upd = wbuf + UPD_S;

  f32x4 acc[4];
  zacc4(acc);

  #pragma unroll 1
  for (int c = 0; c < 2; ++c) {
    #pragma unroll 1
    for (int p = 0; p < 2; ++p) {
      int idx = p * 512 + t;
      int row = idx >> 4;
      int kc = idx & 15;
      int n = n0 + row;
      if (c == 0 || !FUSED_AGG) {
        int ns = n < N_NODES_C ? n : 0;
        const float* src = (c == 0) ? (nodef + (size_t)ns * HD + kc * 8)
                                    : (out + OUT_NODE + (size_t)ns * HD + kc * 8);
        f32x4 v0 = *(const f32x4*)src;
        f32x4 v1 = *(const f32x4*)(src + 4);
        *(int4v*)(B1 + swz(row, kc * 8)) =
            pack8(v0[0], v0[1], v0[2], v0[3], v1[0], v1[1], v1[2], v1[3]);
      } else {
        float a0 = 0.f, a1 = 0.f, a2 = 0.f, a3 = 0.f;
        float a4 = 0.f, a5 = 0.f, a6 = 0.f, a7 = 0.f;
        if (n < N_NODES_C) {
          const int st = offs[n], en = ends[n];
          const short* ub = upd + kc * 8;
          for (int j = st; j < en; ++j) {
            short8 uv = *(const short8*)(ub + (size_t)elist[j] * HD);
            a0 += bf2f(uv[0]); a1 += bf2f(uv[1]); a2 += bf2f(uv[2]); a3 += bf2f(uv[3]);
            a4 += bf2f(uv[4]); a5 += bf2f(uv[5]); a6 += bf2f(uv[6]); a7 += bf2f(uv[7]);
          }
        }
        *(int4v*)(B1 + swz(row, kc * 8)) = pack8(a0, a1, a2, a3, a4, a5, a6, a7);
      }
    }
    __syncthreads();
    mlp16k(B1, wbuf + NW0T, 256, c * 128, acc, lr, kg, w);
    __syncthreads();
  }
  // layer 0 epilogue -> B2
  wb16_bf16(B2, b0, acc, lr, kg, w, true);
  __syncthreads();

  zacc4(acc);
  mlp16k(B2, wbuf + NW1T, 128, 0, acc, lr, kg, w);
  wb16_bf16(B1, b1, acc, lr, kg, w, true);
  __syncthreads();

  zacc4(acc);
  mlp16k(B1, wbuf + NW2T, 128, 0, acc, lr, kg, w);
  wb16_bf16(B2, b2, acc, lr, kg, w, true);
  __syncthreads();

  // layer 3 -> B1 (bf16 h3 + bias, no relu)
  zacc4(acc);
  mlp16k(B2, wbuf + NW3T, 128, 0, acc, lr, kg, w);
  wb16_bf16(B1, b3, acc, lr, kg, w, false);
  __syncthreads();

  // LayerNorm + residual (overwrites agg region with final node output)
  {
    const int row = t >> 3;      // 0..63
    const int q = t & 7;
    const int n = n0 + row;
    const int cxor8 = ((row >> 2) & 3) << 3;
    float hv[16];
    float sum = 0.f, ss = 0.f;
    #pragma unroll
    for (int j = 0; j < 2; ++j) {
      const int truebase = q * 16 + j * 8;
      short8 hb = *(const short8*)(B1 + row * 136 + (truebase ^ cxor8));
      #pragma unroll
      for (int x = 0; x < 8; ++x) {
        float v = bf2f(hb[x]);
        hv[j * 8 + x] = v;
        sum += v;
        ss += v * v;
      }
    }
    sum += __shfl_xor(sum, 1, 64); sum += __shfl_xor(sum, 2, 64); sum += __shfl_xor(sum, 4, 64);
    ss  += __shfl_xor(ss, 1, 64);  ss  += __shfl_xor(ss, 2, 64);  ss  += __shfl_xor(ss, 4, 64);
    const float mu = sum * (1.f / 128.f);
    const float var = ss * (1.f / 128.f) - mu * mu;
    const float rs = rsqrtf(var + 1e-5f);
    if (n < N_NODES_C) {
      #pragma unroll
      for (int j = 0; j < 2; ++j) {
        const int truebase = q * 16 + j * 8;
        #pragma unroll
        for (int h = 0; h < 2; ++h) {
          f32x4 g4 = *(const f32x4*)(gam + truebase + h * 4);
          f32x4 b4 = *(const f32x4*)(bet + truebase + h * 4);
          f32x4 nf4 = *(const f32x4*)(nodef + (size_t)n * HD + truebase + h * 4);
          f32x4 res;
          #pragma unroll
          for (int x = 0; x < 4; ++x)
            res[x] = nf4[x] + (hv[j * 8 + h * 4 + x] - mu) * rs * g4[x] + b4[x];
          *(f32x4*)(out + OUT_NODE + (size_t)n * HD + truebase + h * 4) = res;
        }
      }
    }
  }
}

extern "C" void kernel_launch(void* const* d_in, const int* in_sizes, int n_in,
                              void* d_out, int out_size, void* d_ws, size_t ws_size,
                              hipStream_t stream) {
  const float* nodef = (const float*)d_in[0];
  const float* eattr = (const float*)d_in[1];
  const int*   eidx  = (const int*)d_in[2];
  const float* e_w0 = (const float*)d_in[3];
  const float* e_b0 = (const float*)d_in[4];
  const float* e_w1 = (const float*)d_in[5];
  const float* e_b1 = (const float*)d_in[6];
  const float* e_w2 = (const float*)d_in[7];
  const float* e_b2 = (const float*)d_in[8];
  const float* e_w3 = (const float*)d_in[9];
  const float* e_b3 = (const float*)d_in[10];
  const float* e_g  = (const float*)d_in[11];
  const float* e_be = (const float*)d_in[12];
  const float* n_w0 = (const float*)d_in[13];
  const float* n_b0 = (const float*)d_in[14];
  const float* n_w1 = (const float*)d_in[15];
  const float* n_b1 = (const float*)d_in[16];
  const float* n_w2 = (const float*)d_in[17];
  const float* n_b2 = (const float*)d_in[18];
  const float* n_w3 = (const float*)d_in[19];
  const float* n_b3 = (const float*)d_in[20];
  const float* n_g  = (const float*)d_in[21];
  const float* n_be = (const float*)d_in[22];

  float* out = (float*)d_out;
  short* wbuf = (short*)d_ws;
  const bool has_upd = ws_size >= UPD_END_BYTES;

  hipMemsetAsync((char*)d_ws + (size_t)CURS_I * 4, 0, (size_t)N_NODES_C * 4, stream);
  prep_kernel<<<2048, 256, 0, stream>>>(e_w0, e_w1, e_w2, e_w3, n_w0, n_w1, n_w2, n_w3,
                                        eidx, out, wbuf);
  node_partial_kernel<<<NP_BLOCKS + 1, 512, 0, stream>>>(nodef, wbuf);
  if (has_upd) {
    edge_kernel<true><<<N_EDGES_C / 64, 512, 0, stream>>>(eattr, eidx,
                                                          e_b0, e_b1, e_b2, e_b3, e_g, e_be,
                                                          wbuf, out);
    node_kernel<true><<<(N_NODES_C + 63) / 64, 512, 0, stream>>>(nodef,
                                                                 n_b0, n_b1, n_b2, n_b3, n_g, n_be,
                                                                 wbuf, out);
  } else {
    edge_kernel<false><<<N_EDGES_C / 64, 512, 0, stream>>>(eattr, eidx,
                                                           e_b0, e_b1, e_b2, e_b3, e_g, e_be,
                                                           wbuf, out);
    agg_kernel<<<(N_NODES_C + 3) / 4, 256, 0, stream>>>(eattr, wbuf, out);
    node_kernel<false><<<(N_NODES_C + 63) / 64, 512, 0, stream>>>(nodef,
                                                                  n_b0, n_b1, n_b2, n_b3, n_g, n_be,
                                                                  wbuf, out);
  }
}

// Round 14
// 516.935 us; speedup vs baseline: 1.0320x; 1.0320x over previous
//
#include <hip/hip_runtime.h>

#define N_NODES_C 50000
#define N_EDGES_C 640000
#define HD 128

typedef float f32x4 __attribute__((ext_vector_type(4)));
typedef float f32x2 __attribute__((ext_vector_type(2)));
typedef short short8 __attribute__((ext_vector_type(8)));
typedef int   int4v  __attribute__((ext_vector_type(4)));

// d_out layout (floats): [node_out 6.4M][edge_index 1.28M][edge_out 81.92M]
#define OUT_NODE 0
#define OUT_IDX  6400000
#define OUT_EDGE 7680000

// workspace layout part 1 (shorts = bf16), transposed weights [n][k]
#define EW0T 0        // [0,16384): We^T [128][128]; [16384,49152): WP^T [256][128] (Ws|Wr)
#define WPT  16384
#define EW1T 49152    // 128x128
#define EW2T 65536
#define EW3T 81920
#define NW0T 98304    // 128x256
#define NW1T 131072
#define NW2T 147456
#define NW3T 163840
#define WTOT 180224   // shorts

// workspace layout part 2 (ints; int-index into d_ws)
#define OFFS_I  98304    // 50001 ints: CSR row starts
#define CURS_I  148352   // 50000 ints: counts -> cursor -> row ends
#define ELIST_I 198400   // 640000 ints

// workspace part 3: P table, bf16 [50000][256]
#define PTAB_S 1676800
// workspace part 4 (optional): upd_edge bf16 [640000][128]
#define UPD_S  14476800
#define UPD_END_BYTES ((size_t)(UPD_S + (size_t)N_EDGES_C * HD) * 2)

__device__ inline short f2bf(float f) {
  unsigned u = __builtin_bit_cast(unsigned, f);
  u += 0x7fffu + ((u >> 16) & 1u);   // RNE
  return (short)(u >> 16);
}
__device__ inline float bf2f(short s) {
  unsigned u = ((unsigned)(unsigned short)s) << 16;
  return __builtin_bit_cast(float, u);
}
__device__ inline unsigned cvtpk(float a, float b) {
  unsigned r;
  asm("v_cvt_pk_bf16_f32 %0, %1, %2" : "=v"(r) : "v"(a), "v"(b));
  return r;
}

// LDS index swizzle for bf16 tiles [R][136]: XOR col bits 3-4 with (row>>2)&3 (b128-safe).
__device__ inline int swz(int row, int col) { return row * 136 + (col ^ (((row >> 2) & 3) << 3)); }

// ---------------- prep (+ fused receiver histogram) ----------------
__global__ void prep_kernel(const float* __restrict__ ew0, const float* __restrict__ ew1,
                            const float* __restrict__ ew2, const float* __restrict__ ew3,
                            const float* __restrict__ nw0, const float* __restrict__ nw1,
                            const float* __restrict__ nw2, const float* __restrict__ nw3,
                            const int* __restrict__ eidx,
                            float* __restrict__ out, short* __restrict__ wbuf)
{
  int* counts = (int*)wbuf + CURS_I;   // zeroed by hipMemsetAsync before this kernel
  const int total = 1280000 + WTOT;
  for (int i = blockIdx.x * blockDim.x + threadIdx.x; i < total; i += gridDim.x * blockDim.x) {
    if (i < 1280000) {
      int v = eidx[i];
      out[OUT_IDX + i] = (float)v;
      if (i >= 640000) atomicAdd(&counts[v], 1);   // receiver histogram
    } else {
      int j = i - 1280000;
      short v;
      if (j < WPT)       { int n = j >> 7, k = j & 127; v = f2bf(ew0[(256 + k) * HD + n]); }        // We^T
      else if (j < EW1T) { int j2 = j - WPT, n = j2 >> 7, k = j2 & 127;
                           v = f2bf(ew0[((n < 128 ? 0 : 128) + k) * HD + (n & 127)]); }             // WP^T
      else if (j < EW2T) { int t2 = j - EW1T, n = t2 >> 7, k = t2 & 127; v = f2bf(ew1[k * HD + n]); }
      else if (j < EW3T) { int t2 = j - EW2T, n = t2 >> 7, k = t2 & 127; v = f2bf(ew2[k * HD + n]); }
      else if (j < NW0T) { int t2 = j - EW3T, n = t2 >> 7, k = t2 & 127; v = f2bf(ew3[k * HD + n]); }
      else if (j < NW1T) { int t2 = j - NW0T, n = t2 >> 8, k = t2 & 255; v = f2bf(nw0[k * HD + n]); }
      else if (j < NW2T) { int t2 = j - NW1T, n = t2 >> 7, k = t2 & 127; v = f2bf(nw1[k * HD + n]); }
      else if (j < NW3T) { int t2 = j - NW2T, n = t2 >> 7, k = t2 & 127; v = f2bf(nw2[k * HD + n]); }
      else               { int t2 = j - NW3T, n = t2 >> 7, k = t2 & 127; v = f2bf(nw3[k * HD + n]); }
      wbuf[j] = v;
    }
  }
}

// ---------------- shared 512-thr M=64 helpers (8 waves x 16 cols) ----------------
__device__ inline void zacc4(f32x4 acc[4]) {
  #pragma unroll
  for (int i = 0; i < 4; ++i) { f32x4 z = {0.f, 0.f, 0.f, 0.f}; acc[i] = z; }
}

// A: LDS [64][136] bf16 (swizzled). Wt: [128][Kw] bf16 global (L2-hot). Wave w owns cols w*16..+15.
__device__ inline void mlp16k(const short* __restrict__ Ab, const short* __restrict__ Wt,
                              int Kw, int k0, f32x4 acc[4], int lr, int kg, int w)
{
  const short* wp = Wt + (w * 16 + lr) * Kw + k0 + kg * 8;
  #pragma unroll
  for (int ks = 0; ks < 4; ++ks) {
    short8 b = *(const short8*)(wp + ks * 32);
    #pragma unroll
    for (int mf = 0; mf < 4; ++mf) {
      short8 a = *(const short8*)(Ab + swz(mf * 16 + lr, kg * 8 + ks * 32));
      acc[mf] = __builtin_amdgcn_mfma_f32_16x16x32_bf16(a, b, acc[mf], 0, 0, 0);
    }
  }
}

__device__ inline void wb16_bf16(short* __restrict__ dst, const float* __restrict__ bias,
                                 f32x4 acc[4], int lr, int kg, int w, bool relu)
{
  const int col = w * 16 + lr;
  const float bv = bias[col];
  #pragma unroll
  for (int mf = 0; mf < 4; ++mf) {
    const int row = mf * 16 + kg * 4;
    float v0 = acc[mf][0] + bv, v1 = acc[mf][1] + bv;
    float v2 = acc[mf][2] + bv, v3 = acc[mf][3] + bv;
    if (relu) { v0 = fmaxf(v0, 0.f); v1 = fmaxf(v1, 0.f); v2 = fmaxf(v2, 0.f); v3 = fmaxf(v3, 0.f); }
    unsigned u0 = cvtpk(v0, v1), u1 = cvtpk(v2, v3);
    dst[swz(row + 0, col)] = (short)u0;
    dst[swz(row + 1, col)] = (short)(u0 >> 16);
    dst[swz(row + 2, col)] = (short)u1;
    dst[swz(row + 3, col)] = (short)(u1 >> 16);
  }
}

__device__ inline void wb16_plain(short* __restrict__ dst, f32x4 acc[4], int lr, int kg, int w)
{
  const int col = w * 16 + lr;
  #pragma unroll
  for (int mf = 0; mf < 4; ++mf) {
    const int row = mf * 16 + kg * 4;
    unsigned u0 = cvtpk(acc[mf][0], acc[mf][1]);
    unsigned u1 = cvtpk(acc[mf][2], acc[mf][3]);
    dst[swz(row + 0, col)] = (short)u0;
    dst[swz(row + 1, col)] = (short)(u0 >> 16);
    dst[swz(row + 2, col)] = (short)u1;
    dst[swz(row + 3, col)] = (short)(u1 >> 16);
  }
}

__device__ inline int4v pack8(float a0, float a1, float a2, float a3,
                              float a4, float a5, float a6, float a7) {
  int4v iv;
  iv[0] = (int)cvtpk(a0, a1);
  iv[1] = (int)cvtpk(a2, a3);
  iv[2] = (int)cvtpk(a4, a5);
  iv[3] = (int)cvtpk(a6, a7);
  return iv;
}

// ---------------- node_partial (+ tail-block CSR scan): 512 thr ----------------
#define NP_BLOCKS ((N_NODES_C + 63) / 64)   // 782

__global__ __launch_bounds__(512, 8) void node_partial_kernel(
    const float* __restrict__ nodef, short* __restrict__ wbuf)
{
  __shared__ short lds[2 * 64 * 136];

  // ---- tail block: vectorized CSR scan (counts -> offs + cursor init) ----
  if ((int)blockIdx.x == NP_BLOCKS) {
    int* wsi = (int*)wbuf;
    int* counts = wsi + CURS_I;
    int* offs = wsi + OFFS_I;
    int* tsum = (int*)lds;
    const int t = (int)threadIdx.x;
    const int per = 100;                        // 512*100 >= 50000; 100 % 4 == 0
    const int base = t * per;
    const int lim = (base + per < N_NODES_C) ? base + per : N_NODES_C;
    int s = 0;
    for (int j = base; j < lim; j += 4) {
      int4v c = *(const int4v*)(counts + j);
      s += c[0] + c[1] + c[2] + c[3];
    }
    tsum[t] = s;
    __syncthreads();
    for (int off = 1; off < 512; off <<= 1) {
      int v = tsum[t];
      int add = (t >= off) ? tsum[t - off] : 0;
      __syncthreads();
      tsum[t] = v + add;
      __syncthreads();
    }
    int run = (t == 0) ? 0 : tsum[t - 1];
    for (int j = base; j < lim; j += 4) {
      int4v c = *(const int4v*)(counts + j);
      int4v v;
      v[0] = run; run += c[0];
      v[1] = run; run += c[1];
      v[2] = run; run += c[2];
      v[3] = run; run += c[3];
      *(int4v*)(offs + j) = v;
      *(int4v*)(counts + j) = v;                // cursor init
    }
    if (t == 511) offs[N_NODES_C] = tsum[511];
    return;
  }

  short* B1 = lds;
  short* B2 = lds + 64 * 136;
  short* ptab = wbuf + PTAB_S;

  const int t = (int)threadIdx.x;
  const int lane = t & 63;
  const int w = t >> 6;
  const int lr = lane & 15;
  const int kg = lane >> 4;
  const int n0 = (int)blockIdx.x * 64;

  #pragma unroll
  for (int p = 0; p < 2; ++p) {
    int idx = p * 512 + t;
    int row = idx >> 4;
    int kc = idx & 15;
    int n = n0 + row;
    int ns = n < N_NODES_C ? n : 0;
    const float* src = nodef + (size_t)ns * HD + kc * 8;
    f32x4 v0 = *(const f32x4*)src;
    f32x4 v1 = *(const f32x4*)(src + 4);
    *(int4v*)(B1 + swz(row, kc * 8)) =
        pack8(v0[0], v0[1], v0[2], v0[3], v1[0], v1[1], v1[2], v1[3]);
  }
  __syncthreads();

  f32x4 acc[4];
  #pragma unroll 1
  for (int h = 0; h < 2; ++h) {
    zacc4(acc);
    mlp16k(B1, wbuf + WPT + h * (128 * 128), 128, 0, acc, lr, kg, w);
    wb16_plain(B2, acc, lr, kg, w);
    __syncthreads();
    #pragma unroll
    for (int p = 0; p < 2; ++p) {
      int idx = p * 512 + t;
      int row = idx >> 4;
      int kc = idx & 15;
      int n = n0 + row;
      if (n < N_NODES_C) {
        short8 sv = *(const short8*)(B2 + swz(row, kc * 8));
        *(short8*)(ptab + (size_t)n * 256 + h * 128 + kc * 8) = sv;
      }
    }
    __syncthreads();
  }
}

// ---------------- edge kernel: M=64, 512 thr, bf16 h3 epilogue, epilogue-fused CSR-fill ----------------
template<bool WRITE_UPD>
__global__ __launch_bounds__(512, 8) void edge_kernel(
    const float* __restrict__ eattr, const int* __restrict__ eidx,
    const float* __restrict__ b0, const float* __restrict__ b1,
    const float* __restrict__ b2, const float* __restrict__ b3,
    const float* __restrict__ gam, const float* __restrict__ bet,
    short* __restrict__ wbuf, float* __restrict__ out)
{
  __shared__ short lds[2 * 64 * 136];   // 34816 B -> 4 blocks/CU -> 32 waves/CU
  short* B1 = lds;
  short* B2 = lds + 64 * 136;

  const int t = (int)threadIdx.x;
  const int w = t >> 6;                 // 0..7
  const int lane = t & 63;
  const int lr = lane & 15;
  const int kg = lane >> 4;
  const int e0 = (int)blockIdx.x * 64;
  const int* senders = eidx;
  const int* recvs = eidx + N_EDGES_C;
  const short* ptab = wbuf + PTAB_S;
  short* upd = wbuf + UPD_S;
  int* wsi = (int*)wbuf;
  int* cursor = wsi + CURS_I;
  int* elist = wsi + ELIST_I;

  f32x4 acc[4];

  // ---- stage: eattr -> B1 (bf16), G = Ps[s]+Pr[r] -> B2 (bf16) ----
  #pragma unroll
  for (int p = 0; p < 2; ++p) {
    int idx = p * 512 + t;
    int row = idx >> 4;
    int kc = idx & 15;
    int e = e0 + row;
    const float* src = eattr + (size_t)e * HD + kc * 8;
    f32x4 v0 = *(const f32x4*)src;
    f32x4 v1 = *(const f32x4*)(src + 4);
    *(int4v*)(B1 + swz(row, kc * 8)) =
        pack8(v0[0], v0[1], v0[2], v0[3], v1[0], v1[1], v1[2], v1[3]);

    int s = senders[e], r = recvs[e];
    short8 ps = *(const short8*)(ptab + (size_t)s * 256 + kc * 8);
    short8 pr = *(const short8*)(ptab + (size_t)r * 256 + 128 + kc * 8);
    float g0 = bf2f(ps[0]) + bf2f(pr[0]), g1 = bf2f(ps[1]) + bf2f(pr[1]);
    float g2 = bf2f(ps[2]) + bf2f(pr[2]), g3 = bf2f(ps[3]) + bf2f(pr[3]);
    float g4 = bf2f(ps[4]) + bf2f(pr[4]), g5 = bf2f(ps[5]) + bf2f(pr[5]);
    float g6 = bf2f(ps[6]) + bf2f(pr[6]), g7 = bf2f(ps[7]) + bf2f(pr[7]);
    *(int4v*)(B2 + swz(row, kc * 8)) = pack8(g0, g1, g2, g3, g4, g5, g6, g7);
  }
  __syncthreads();

  // ---- layer 0: Ep = eattr @ We^T; h0 = relu(Ep + G + b0) -> B2 ----
  zacc4(acc);
  mlp16k(B1, wbuf + EW0T, 128, 0, acc, lr, kg, w);
  {
    const int col = w * 16 + lr;
    const float bv = b0[col];
    #pragma unroll
    for (int mf = 0; mf < 4; ++mf) {
      const int row = mf * 16 + kg * 4;
      float v0 = fmaxf(acc[mf][0] + bf2f(B2[swz(row + 0, col)]) + bv, 0.f);
      float v1 = fmaxf(acc[mf][1] + bf2f(B2[swz(row + 1, col)]) + bv, 0.f);
      float v2 = fmaxf(acc[mf][2] + bf2f(B2[swz(row + 2, col)]) + bv, 0.f);
      float v3 = fmaxf(acc[mf][3] + bf2f(B2[swz(row + 3, col)]) + bv, 0.f);
      unsigned u0 = cvtpk(v0, v1), u1 = cvtpk(v2, v3);
      B2[swz(row + 0, col)] = (short)u0;
      B2[swz(row + 1, col)] = (short)(u0 >> 16);
      B2[swz(row + 2, col)] = (short)u1;
      B2[swz(row + 3, col)] = (short)(u1 >> 16);
    }
  }
  __syncthreads();

  // ---- layer 1: B2 -> B1 ----
  zacc4(acc);
  mlp16k(B2, wbuf + EW1T, 128, 0, acc, lr, kg, w);
  wb16_bf16(B1, b1, acc, lr, kg, w, true);
  __syncthreads();

  // ---- layer 2: B1 -> B2 ----
  zacc4(acc);
  mlp16k(B1, wbuf + EW2T, 128, 0, acc, lr, kg, w);
  wb16_bf16(B2, b2, acc, lr, kg, w, true);
  __syncthreads();

  // ---- layer 3: B2 -> B1 (bf16 h3 + bias, no relu) ----
  zacc4(acc);
  mlp16k(B2, wbuf + EW3T, 128, 0, acc, lr, kg, w);
  wb16_bf16(B1, b3, acc, lr, kg, w, false);
  __syncthreads();

  // ---- LayerNorm + residual store (+ upd bf16, + epilogue-fused CSR-fill) ----
  {
    const int row = t >> 3;      // 0..63
    const int q = t & 7;         // 8 threads/row, 16 cols each
    const int e = e0 + row;

    // fused fill: one thread per edge places e into its receiver's CSR slot
    if (q == 0) {
      int r = recvs[e];
      int pos = atomicAdd(&cursor[r], 1);
      elist[pos] = e;
    }

    const int cxor8 = ((row >> 2) & 3) << 3;   // swz col XOR (8-block preserving)
    float hv[16];
    float sum = 0.f, ss = 0.f;
    #pragma unroll
    for (int j = 0; j < 2; ++j) {
      const int truebase = q * 16 + j * 8;
      short8 hb = *(const short8*)(B1 + row * 136 + (truebase ^ cxor8));
      #pragma unroll
      for (int x = 0; x < 8; ++x) {
        float v = bf2f(hb[x]);
        hv[j * 8 + x] = v;
        sum += v;
        ss += v * v;
      }
    }
    sum += __shfl_xor(sum, 1, 64); sum += __shfl_xor(sum, 2, 64); sum += __shfl_xor(sum, 4, 64);
    ss  += __shfl_xor(ss, 1, 64);  ss  += __shfl_xor(ss, 2, 64);  ss  += __shfl_xor(ss, 4, 64);
    const float mu = sum * (1.f / 128.f);
    const float var = ss * (1.f / 128.f) - mu * mu;
    const float rs = rsqrtf(var + 1e-5f);
    #pragma unroll
    for (int j = 0; j < 2; ++j) {
      const int truebase = q * 16 + j * 8;
      float o[8];
      #pragma unroll
      for (int h = 0; h < 2; ++h) {
        f32x4 g4 = *(const f32x4*)(gam + truebase + h * 4);
        f32x4 b4 = *(const f32x4*)(bet + truebase + h * 4);
        f32x4 ea = *(const f32x4*)(eattr + (size_t)e * HD + truebase + h * 4);
        f32x4 res;
        #pragma unroll
        for (int x = 0; x < 4; ++x) {
          float ov = (hv[j * 8 + h * 4 + x] - mu) * rs * g4[x] + b4[x];
          o[h * 4 + x] = ov;
          res[x] = ea[x] + ov;
        }
        *(f32x4*)(out + OUT_EDGE + (size_t)e * HD + truebase + h * 4) = res;
      }
      if (WRITE_UPD) {
        int4v uu;
        uu[0] = (int)cvtpk(o[0], o[1]);
        uu[1] = (int)cvtpk(o[2], o[3]);
        uu[2] = (int)cvtpk(o[4], o[5]);
        uu[3] = (int)cvtpk(o[6], o[7]);
        *(int4v*)(upd + (size_t)e * HD + truebase) = uu;
      }
    }
  }
}

// ---------------- agg fallback: reads edge_out and eattr (f32), subtracts ----------------
__global__ __launch_bounds__(256, 8) void agg_kernel(
    const float* __restrict__ eattr, const short* __restrict__ wbuf,
    float* __restrict__ out)
{
  const int* wsi = (const int*)wbuf;
  const int* offs = wsi + OFFS_I;
  const int* ends = wsi + CURS_I;
  const int* elist = wsi + ELIST_I;

  const int t = (int)threadIdx.x;
  const int lane = t & 63;
  const int n = (int)blockIdx.x * 4 + (t >> 6);
  if (n >= N_NODES_C) return;

  const int start = offs[n];
  const int end = ends[n];
  f32x2 acc0 = {0.f, 0.f};
  f32x2 acc1 = {0.f, 0.f};
  const float* eo_base = out + OUT_EDGE + lane * 2;
  const float* ea_base = eattr + lane * 2;
  int j = start;
  for (; j + 1 < end; j += 2) {
    const int ex = elist[j];
    const int ey = elist[j + 1];
    f32x2 eox = *(const f32x2*)(eo_base + (size_t)ex * HD);
    f32x2 eax = *(const f32x2*)(ea_base + (size_t)ex * HD);
    f32x2 eoy = *(const f32x2*)(eo_base + (size_t)ey * HD);
    f32x2 eay = *(const f32x2*)(ea_base + (size_t)ey * HD);
    acc0[0] += eox[0] - eax[0];
    acc0[1] += eox[1] - eax[1];
    acc1[0] += eoy[0] - eay[0];
    acc1[1] += eoy[1] - eay[1];
  }
  if (j < end) {
    const int ex = elist[j];
    f32x2 eox = *(const f32x2*)(eo_base + (size_t)ex * HD);
    f32x2 eax = *(const f32x2*)(ea_base + (size_t)ex * HD);
    acc0[0] += eox[0] - eax[0];
    acc0[1] += eox[1] - eax[1];
  }
  acc0[0] += acc1[0];
  acc0[1] += acc1[1];
  *(f32x2*)(out + OUT_NODE + (size_t)n * HD + lane * 2) = acc0;
}

// ---------------- node kernel: M=64, 512 thr (FUSED_AGG gathers upd via CSR in c=1) ----------------
template<bool FUSED_AGG>
__global__ __launch_bounds__(512, 8) void node_kernel(
    const float* __restrict__ nodef,
    const float* __restrict__ b0, const float* __restrict__ b1,
    const float* __restrict__ b2, const float* __restrict__ b3,
    const float* __restrict__ gam, const float* __restrict__ bet,
    const short* __restrict__ wbuf, float* __restrict__ out)
{
  __shared__ short lds[2 * 64 * 136];
  short* B1 = lds;
  short* B2 = lds + 64 * 136;

  const int t = (int)threadIdx.x;
  const int lane = t & 63;
  const int w = t >> 6;
  const int lr = lane & 15;
  const int kg = lane >> 4;
  const int n0 = (int)blockIdx.x * 64;

  const int* wsi = (const int*)wbuf;
  const int* offs = wsi + OFFS_I;
  const int* ends = wsi + CURS_I;
  const int* elist = wsi + ELIST_I;
  const short* upd = wbuf + UPD_S;

  f32x4 acc[4];
  zacc4(acc);

  #pragma unroll 1
  for (int c = 0; c < 2; ++c) {
    #pragma unroll 1
    for (int p = 0; p < 2; ++p) {
      int idx = p * 512 + t;
      int row = idx >> 4;
      int kc = idx & 15;
      int n = n0 + row;
      if (c == 0 || !FUSED_AGG) {
        int ns = n < N_NODES_C ? n : 0;
        const float* src = (c == 0) ? (nodef + (size_t)ns * HD + kc * 8)
                                    : (out + OUT_NODE + (size_t)ns * HD + kc * 8);
        f32x4 v0 = *(const f32x4*)src;
        f32x4 v1 = *(const f32x4*)(src + 4);
        *(int4v*)(B1 + swz(row, kc * 8)) =
            pack8(v0[0], v0[1], v0[2], v0[3], v1[0], v1[1], v1[2], v1[3]);
      } else {
        float a0 = 0.f, a1 = 0.f, a2 = 0.f, a3 = 0.f;
        float a4 = 0.f, a5 = 0.f, a6 = 0.f, a7 = 0.f;
        if (n < N_NODES_C) {
          const int st = offs[n], en = ends[n];
          const short* ub = upd + kc * 8;
          for (int j = st; j < en; ++j) {
            short8 uv = *(const short8*)(ub + (size_t)elist[j] * HD);
            a0 += bf2f(uv[0]); a1 += bf2f(uv[1]); a2 += bf2f(uv[2]); a3 += bf2f(uv[3]);
            a4 += bf2f(uv[4]); a5 += bf2f(uv[5]); a6 += bf2f(uv[6]); a7 += bf2f(uv[7]);
          }
        }
        *(int4v*)(B1 + swz(row, kc * 8)) = pack8(a0, a1, a2, a3, a4, a5, a6, a7);
      }
    }
    __syncthreads();
    mlp16k(B1, wbuf + NW0T, 256, c * 128, acc, lr, kg, w);
    __syncthreads();
  }
  // layer 0 epilogue -> B2
  wb16_bf16(B2, b0, acc, lr, kg, w, true);
  __syncthreads();

  zacc4(acc);
  mlp16k(B2, wbuf + NW1T, 128, 0, acc, lr, kg, w);
  wb16_bf16(B1, b1, acc, lr, kg, w, true);
  __syncthreads();

  zacc4(acc);
  mlp16k(B1, wbuf + NW2T, 128, 0, acc, lr, kg, w);
  wb16_bf16(B2, b2, acc, lr, kg, w, true);
  __syncthreads();

  // layer 3 -> B1 (bf16 h3 + bias, no relu)
  zacc4(acc);
  mlp16k(B2, wbuf + NW3T, 128, 0, acc, lr, kg, w);
  wb16_bf16(B1, b3, acc, lr, kg, w, false);
  __syncthreads();

  // LayerNorm + residual (overwrites agg region with final node output)
  {
    const int row = t >> 3;      // 0..63
    const int q = t & 7;
    const int n = n0 + row;
    const int cxor8 = ((row >> 2) & 3) << 3;
    float hv[16];
    float sum = 0.f, ss = 0.f;
    #pragma unroll
    for (int j = 0; j < 2; ++j) {
      const int truebase = q * 16 + j * 8;
      short8 hb = *(const short8*)(B1 + row * 136 + (truebase ^ cxor8));
      #pragma unroll
      for (int x = 0; x < 8; ++x) {
        float v = bf2f(hb[x]);
        hv[j * 8 + x] = v;
        sum += v;
        ss += v * v;
      }
    }
    sum += __shfl_xor(sum, 1, 64); sum += __shfl_xor(sum, 2, 64); sum += __shfl_xor(sum, 4, 64);
    ss  += __shfl_xor(ss, 1, 64);  ss  += __shfl_xor(ss, 2, 64);  ss  += __shfl_xor(ss, 4, 64);
    const float mu = sum * (1.f / 128.f);
    const float var = ss * (1.f / 128.f) - mu * mu;
    const float rs = rsqrtf(var + 1e-5f);
    if (n < N_NODES_C) {
      #pragma unroll
      for (int j = 0; j < 2; ++j) {
        const int truebase = q * 16 + j * 8;
        #pragma unroll
        for (int h = 0; h < 2; ++h) {
          f32x4 g4 = *(const f32x4*)(gam + truebase + h * 4);
          f32x4 b4 = *(const f32x4*)(bet + truebase + h * 4);
          f32x4 nf4 = *(const f32x4*)(nodef + (size_t)n * HD + truebase + h * 4);
          f32x4 res;
          #pragma unroll
          for (int x = 0; x < 4; ++x)
            res[x] = nf4[x] + (hv[j * 8 + h * 4 + x] - mu) * rs * g4[x] + b4[x];
          *(f32x4*)(out + OUT_NODE + (size_t)n * HD + truebase + h * 4) = res;
        }
      }
    }
  }
}

extern "C" void kernel_launch(void* const* d_in, const int* in_sizes, int n_in,
                              void* d_out, int out_size, void* d_ws, size_t ws_size,
                              hipStream_t stream) {
  const float* nodef = (const float*)d_in[0];
  const float* eattr = (const float*)d_in[1];
  const int*   eidx  = (const int*)d_in[2];
  const float* e_w0 = (const float*)d_in[3];
  const float* e_b0 = (const float*)d_in[4];
  const float* e_w1 = (const float*)d_in[5];
  const float* e_b1 = (const float*)d_in[6];
  const float* e_w2 = (const float*)d_in[7];
  const float* e_b2 = (const float*)d_in[8];
  const float* e_w3 = (const float*)d_in[9];
  const float* e_b3 = (const float*)d_in[10];
  const float* e_g  = (const float*)d_in[11];
  const float* e_be = (const float*)d_in[12];
  const float* n_w0 = (const float*)d_in[13];
  const float* n_b0 = (const float*)d_in[14];
  const float* n_w1 = (const float*)d_in[15];
  const float* n_b1 = (const float*)d_in[16];
  const float* n_w2 = (const float*)d_in[17];
  const float* n_b2 = (const float*)d_in[18];
  const float* n_w3 = (const float*)d_in[19];
  const float* n_b3 = (const float*)d_in[20];
  const float* n_g  = (const float*)d_in[21];
  const float* n_be = (const float*)d_in[22];

  float* out = (float*)d_out;
  short* wbuf = (short*)d_ws;
  const bool has_upd = ws_size >= UPD_END_BYTES;

  hipMemsetAsync((char*)d_ws + (size_t)CURS_I * 4, 0, (size_t)N_NODES_C * 4, stream);
  prep_kernel<<<2048, 256, 0, stream>>>(e_w0, e_w1, e_w2, e_w3, n_w0, n_w1, n_w2, n_w3,
                                        eidx, out, wbuf);
  node_partial_kernel<<<NP_BLOCKS + 1, 512, 0, stream>>>(nodef, wbuf);
  if (has_upd) {
    edge_kernel<true><<<N_EDGES_C / 64, 512, 0, stream>>>(eattr, eidx,
                                                          e_b0, e_b1, e_b2, e_b3, e_g, e_be,
                                                          wbuf, out);
    node_kernel<true><<<(N_NODES_C + 63) / 64, 512, 0, stream>>>(nodef,
                                                                 n_b0, n_b1, n_b2, n_b3, n_g, n_be,
                                                                 wbuf, out);
  } else {
    edge_kernel<false><<<N_EDGES_C / 64, 512, 0, stream>>>(eattr, eidx,
                                                           e_b0, e_b1, e_b2, e_b3, e_g, e_be,
                                                           wbuf, out);
    agg_kernel<<<(N_NODES_C + 3) / 4, 256, 0, stream>>>(eattr, wbuf, out);
    node_kernel<false><<<(N_NODES_C + 63) / 64, 512, 0, stream>>>(nodef,
                                                                  n_b0, n_b1, n_b2, n_b3, n_g, n_be,
                                                                  wbuf, out);
  }
}